// Round 3
// baseline (538.334 us; speedup 1.0000x reference)
//
#include <hip/hip_runtime.h>
#include <math.h>

#define NPTS 32768
#define NIMG 32          // B*C = 8*4

// ---------- I0 Bessel (double, for setup) ----------
static __device__ __forceinline__ double bessel_i0d(double x) {
    double hx2 = 0.25 * x * x;
    double t = 1.0, s = 1.0;
#pragma unroll
    for (int m = 1; m <= 40; ++m) {
        t *= hx2 * (1.0 / ((double)m * (double)m));
        s += t;
    }
    return s;
}

// ---------- I0 Bessel (float) ----------
static __device__ __forceinline__ float bessel_i0f(float x) {
    float hx2 = 0.25f * x * x;
    float t = 1.0f, s = 1.0f;
#pragma unroll
    for (int m = 1; m <= 30; ++m) {
        t *= hx2 * (1.0f / ((float)m * (float)m));
        s += t;
    }
    return s;
}

// ---------- S[d] = sum_{x<128} ax[x] * exp(2*pi*i * x * d / 256) ----------
__global__ void k_setup_S(float2* __restrict__ S) {
    __shared__ float ax[128];
    int t = threadIdx.x;              // 0..255
    if (t < 128) {
        double i0a = bessel_i0d(14.04);
        double om = ((double)t - 63.5) * (1.0 / 256.0);
        double pj = M_PI * 6.0 * om;
        double tt = sqrt(14.04 * 14.04 - pj * pj);   // always real here
        double kbft = 6.0 * (sinh(tt) / tt) / i0a;
        ax[t] = (float)(1.0 / kbft);                 // apodization 1D
    }
    __syncthreads();
    double re = 0.0, im = 0.0;
    for (int x = 0; x < 128; ++x) {
        int ph = (x * t) & 255;                      // exact phase reduction
        double ang = (double)ph * (2.0 * M_PI / 256.0);
        re += (double)ax[x] * cos(ang);
        im += (double)ax[x] * sin(ang);
    }
    S[t] = make_float2((float)re, (float)im);
}

// ---------- per-point 1D weights: wxy[k*12 + dim*6 + j] ----------
__global__ void k_weights(const float* __restrict__ coords, float* __restrict__ wxy) {
    int id = blockIdx.x * blockDim.x + threadIdx.x;   // (k,dim)
    if (id >= NPTS * 2) return;
    int k = id >> 1, dim = id & 1;
    const float inv_i0a = 1.0f / bessel_i0f(14.04f);  // constant-folds
    float gm = coords[2 * k + dim] * (float)(256.0 / (2.0 * M_PI));
    float b = floorf(gm - 3.0f);
#pragma unroll
    for (int j = 0; j < 6; ++j) {
        float u = gm - (b + (float)(j + 1));
        float r = u * (1.0f / 3.0f);
        float arg = 1.0f - r * r;
        float w = (arg > 0.0f) ? bessel_i0f(14.04f * sqrtf(arg)) * inv_i0a : 0.0f;
        wxy[k * 12 + dim * 6 + j] = w;
    }
}

// ---------- bin point ids per 16x16 tile (<=4 tiles per point) ----------
__global__ void k_bin(const float* __restrict__ coords,
                      unsigned* __restrict__ tileCount,   // stride 16 (line-padded)
                      unsigned* __restrict__ bins) {      // 256 tiles x 512 slots
    int k = blockIdx.x * blockDim.x + threadIdx.x;
    if (k >= NPTS) return;
    float gmx = coords[2 * k]     * (float)(256.0 / (2.0 * M_PI));
    float gmy = coords[2 * k + 1] * (float)(256.0 / (2.0 * M_PI));
    int x0 = (((int)floorf(gmx - 3.0f)) + 1 + 512) & 255;
    int y0 = (((int)floorf(gmy - 3.0f)) + 1 + 512) & 255;
    int tx0 = x0 >> 4, tx1 = ((x0 + 5) & 255) >> 4;
    int ty0 = y0 >> 4, ty1 = ((y0 + 5) & 255) >> 4;
    int nx = (tx1 == tx0) ? 1 : 2;
    int ny = (ty1 == ty0) ? 1 : 2;
    int txs[2] = {tx0, tx1}, tys[2] = {ty0, ty1};
    for (int i = 0; i < nx; ++i)
        for (int j = 0; j < ny; ++j) {
            int tile = txs[i] * 16 + tys[j];
            unsigned pos = atomicAdd(&tileCount[tile * 16], 1u);
            if (pos < 512u) bins[tile * 512 + pos] = (unsigned)k;
        }
}

// ---------- transpose values [img][k] -> vt [k][img] ----------
__global__ void k_transpose(const float* __restrict__ values, float* __restrict__ vt) {
    __shared__ float tile[32][257];
    int kbase = blockIdx.x * 256;
    int t = threadIdx.x;
    for (int img = 0; img < 32; ++img)
        tile[img][t] = values[img * NPTS + kbase + t];
    __syncthreads();
    int img = t & 31;
    int k0 = t >> 5;                   // 0..7
    for (int r = 0; r < 32; ++r) {
        int kl = k0 + r * 8;           // 0..255
        vt[(kbase + kl) * 32 + img] = tile[img][kl];
    }
}

// ---------- tile gather: LDS accumulation, no global atomics ----------
__global__ __launch_bounds__(256) void k_gather_tile(
        const float* __restrict__ coords, const float* __restrict__ wxy,
        const float* __restrict__ vt,
        const unsigned* __restrict__ tileCount, const unsigned* __restrict__ bins,
        float* __restrict__ grid) {
    __shared__ float accum[256 * 33];      // [cell_local][img] pad 33
    __shared__ unsigned wc[64 * 36];       // packed (w:16 | cell:8) per (pt,tap)
    __shared__ unsigned skl[64];
    int tile = blockIdx.x;
    int TX = tile >> 4, TY = tile & 15;
    int t = threadIdx.x;
    for (int i = t; i < 256 * 33; i += 256) accum[i] = 0.0f;
    unsigned n = tileCount[tile * 16];
    if (n > 512u) n = 512u;
    int img = t & 31;
    for (unsigned base = 0; base < n; base += 64) {
        int m = (int)((n - base < 64u) ? (n - base) : 64u);
        __syncthreads();                    // protect skl/wc from prev iter readers
        if (t < m) skl[t] = bins[tile * 512 + base + t];
        __syncthreads();
        // stage A: pack taps
        for (int idx = t; idx < m * 36; idx += 256) {
            int pi = idx / 36;
            int tap = idx - pi * 36;
            int jx = tap / 6, jy = tap - jx * 6;
            unsigned k = skl[pi];
            float gmx = coords[2 * k]     * (float)(256.0 / (2.0 * M_PI));
            float gmy = coords[2 * k + 1] * (float)(256.0 / (2.0 * M_PI));
            int cx = (((int)floorf(gmx - 3.0f)) + 1 + jx + 512) & 255;
            int cy = (((int)floorf(gmy - 3.0f)) + 1 + jy + 512) & 255;
            bool in = ((cx >> 4) == TX) && ((cy >> 4) == TY);
            unsigned pack = 0u;
            if (in) {
                float w = wxy[k * 12 + jx] * wxy[k * 12 + 6 + jy];
                unsigned q = (unsigned)(w * 65535.0f + 0.5f);
                if (q > 65535u) q = 65535u;
                unsigned cl = (unsigned)(((cx & 15) << 4) | (cy & 15));
                pack = (q << 8) | cl;
            }
            wc[idx] = pack;
        }
        __syncthreads();
        // stage B: accumulate
        for (int g = 0; g < m; g += 8) {
            int pt = g + (t >> 5);
            float v = 0.0f;
            if (pt < m) v = vt[skl[pt] * 32 + img];
#pragma unroll
            for (int tap = 0; tap < 36; ++tap) {
                unsigned pack = wc[pt * 36 + tap];     // broadcast per 32 lanes
                float w = (float)(pack >> 8) * (1.0f / 65535.0f);
                unsigned cl = pack & 255u;
                atomicAdd(&accum[cl * 33 + img], w * v);
            }
        }
    }
    __syncthreads();
    // writeout: cell_local t -> global cell
    int gc = ((TX << 4) + (t >> 4)) * 256 + (TY << 4) + (t & 15);
    for (int im2 = 0; im2 < 32; ++im2)
        grid[im2 * 65536 + gc] = accum[t * 33 + im2];
}

// ---------- mm1: T1[img,p,v] = sum_u S[(u-2p)&255] * G[img,u,v] ----------
__global__ void k_mm1(const float* __restrict__ grid, const float2* __restrict__ S,
                      float2* __restrict__ T1) {
    __shared__ float2 ssh[256];
    int v = threadIdx.x;          // 0..255
    int img = blockIdx.x;         // 0..31
    int p0 = blockIdx.y * 4;      // 4 p-rows per block
    ssh[v] = S[v];
    __syncthreads();
    const float* g = grid + img * 65536;
    float re[4] = {0, 0, 0, 0}, im[4] = {0, 0, 0, 0};
    for (int u = 0; u < 256; ++u) {
        float gv = g[(u << 8) + v];
#pragma unroll
        for (int i = 0; i < 4; ++i) {
            float2 s = ssh[(u - 2 * (p0 + i)) & 255];
            re[i] += s.x * gv;
            im[i] += s.y * gv;
        }
    }
#pragma unroll
    for (int i = 0; i < 4; ++i)
        T1[((img * 128 + p0 + i) << 8) + v] = make_float2(re[i], im[i]);
}

// ---------- mm2: F[img,p,q] = sum_v T1[img,p,v] * S[(v-2q)&255]; |F| + fftshift ----------
__global__ void k_mm2(const float2* __restrict__ T1, const float2* __restrict__ S,
                      float* __restrict__ out) {
    __shared__ float sre[256], sim[256];
    __shared__ float2 trow[256];
    int q = threadIdx.x;          // 0..127
    int img = blockIdx.x;         // 0..31
    int p = blockIdx.y;           // 0..127
    float2 s0 = S[q];       sre[q] = s0.x;        sim[q] = s0.y;
    float2 s1 = S[q + 128]; sre[q + 128] = s1.x;  sim[q + 128] = s1.y;
    const float2* tr = T1 + (img * 128 + p) * 256;
    trow[q] = tr[q];
    trow[q + 128] = tr[q + 128];
    __syncthreads();
    float re = 0.f, im = 0.f;
    for (int v = 0; v < 256; ++v) {
        float2 t = trow[v];                  // wave-uniform -> LDS broadcast
        int si = (v - 2 * q) & 255;
        float srv = sre[si], siv = sim[si];
        re += t.x * srv - t.y * siv;
        im += t.x * siv + t.y * srv;
    }
    float mag = sqrtf(re * re + im * im);
    int b = img >> 2, c = img & 3;
    out[((((b ^ 4) * 4 + (c ^ 2)) * 128 + (p ^ 64)) << 7) + (q ^ 64)] = mag;
}

extern "C" void kernel_launch(void* const* d_in, const int* in_sizes, int n_in,
                              void* d_out, int out_size, void* d_ws, size_t ws_size,
                              hipStream_t stream) {
    const float* values = (const float*)d_in[0];   // [8,4,32768] f32
    const float* coords = (const float*)d_in[1];   // [32768,2] f32

    char* ws = (char*)d_ws;
    // layout (peak 16.85 MB):
    float2*   S         = (float2*)(ws + 0);             // [0, 4K)
    unsigned* tileCount = (unsigned*)(ws + 4096);        // [4K, 20.5K)  256x16 u32
    float*    wxy       = (float*)(ws + 20480);          // [20K, 1.6M)  32768x12 f32
    float*    grid      = (float*)(ws + 1622016);        // 8 MB -> ends 10010624
    // region overlapping T1 (vt/bins dead before mm1 writes T1):
    float2*   T1        = (float2*)(ws + 10010624);      // 8 MB -> ends 18399232
    float*    vt        = (float*)(ws + 10010624);       // 4 MB
    unsigned* bins      = (unsigned*)(ws + 14204928);    // 512 KB

    hipMemsetAsync(tileCount, 0, 256 * 16 * sizeof(unsigned), stream);

    k_setup_S<<<1, 256, 0, stream>>>(S);
    k_weights<<<(NPTS * 2 + 255) / 256, 256, 0, stream>>>(coords, wxy);
    k_bin<<<(NPTS + 255) / 256, 256, 0, stream>>>(coords, tileCount, bins);
    k_transpose<<<NPTS / 256, 256, 0, stream>>>(values, vt);
    k_gather_tile<<<256, 256, 0, stream>>>(coords, wxy, vt, tileCount, bins, grid);
    k_mm1<<<dim3(32, 32), 256, 0, stream>>>(grid, S, T1);
    k_mm2<<<dim3(32, 128), 128, 0, stream>>>(T1, S, (float*)d_out);
}

// Round 4
// 162.974 us; speedup vs baseline: 3.3032x; 3.3032x over previous
//
#include <hip/hip_runtime.h>
#include <math.h>

#define NPTS 32768
#define NIMG 32          // B*C = 8*4
#define CAPP 192         // per-tile point capacity (mean ~85, max ~126)
#define CAPC 57          // per-cell entry capacity (mean ~18, max ~46); odd -> bank-conflict-free
#define SCALE ((float)(256.0 / (2.0 * M_PI)))

// ---------- I0 Bessel (double, for setup) ----------
static __device__ __forceinline__ double bessel_i0d(double x) {
    double hx2 = 0.25 * x * x;
    double t = 1.0, s = 1.0;
#pragma unroll
    for (int m = 1; m <= 40; ++m) {
        t *= hx2 * (1.0 / ((double)m * (double)m));
        s += t;
    }
    return s;
}

// ---------- I0 Bessel (float) ----------
static __device__ __forceinline__ float bessel_i0f(float x) {
    float hx2 = 0.25f * x * x;
    float t = 1.0f, s = 1.0f;
#pragma unroll
    for (int m = 1; m <= 30; ++m) {
        t *= hx2 * (1.0f / ((float)m * (float)m));
        s += t;
    }
    return s;
}

// ---------- S[d] = sum_{x<128} ax[x] * exp(2*pi*i * x * d / 256) ----------
__global__ void k_setup_S(float2* __restrict__ S) {
    __shared__ float ax[128];
    int t = threadIdx.x;              // 0..255
    if (t < 128) {
        double i0a = bessel_i0d(14.04);
        double om = ((double)t - 63.5) * (1.0 / 256.0);
        double pj = M_PI * 6.0 * om;
        double tt = sqrt(14.04 * 14.04 - pj * pj);   // always real here
        double kbft = 6.0 * (sinh(tt) / tt) / i0a;
        ax[t] = (float)(1.0 / kbft);                 // apodization 1D
    }
    __syncthreads();
    double re = 0.0, im = 0.0;
    for (int x = 0; x < 128; ++x) {
        int ph = (x * t) & 255;                      // exact phase reduction
        double ang = (double)ph * (2.0 * M_PI / 256.0);
        re += (double)ax[x] * cos(ang);
        im += (double)ax[x] * sin(ang);
    }
    S[t] = make_float2((float)re, (float)im);
}

// ---------- per-point 1D weights: wxy[k*12 + dim*6 + j] ----------
__global__ void k_weights(const float* __restrict__ coords, float* __restrict__ wxy) {
    int id = blockIdx.x * blockDim.x + threadIdx.x;   // (k,dim)
    if (id >= NPTS * 2) return;
    int k = id >> 1, dim = id & 1;
    const float inv_i0a = 1.0f / bessel_i0f(14.04f);  // constant-folds
    float gm = coords[2 * k + dim] * SCALE;
    float b = floorf(gm - 3.0f);
#pragma unroll
    for (int j = 0; j < 6; ++j) {
        float u = gm - (b + (float)(j + 1));
        float r = u * (1.0f / 3.0f);
        float arg = 1.0f - r * r;
        float w = (arg > 0.0f) ? bessel_i0f(14.04f * sqrtf(arg)) * inv_i0a : 0.0f;
        wxy[k * 12 + dim * 6 + j] = w;
    }
}

// ---------- bin point ids per 8x8 tile (<=4 tiles per point) ----------
__global__ void k_bin(const float* __restrict__ coords,
                      unsigned* __restrict__ tileCount,   // [1024]
                      unsigned* __restrict__ bins) {      // [1024][CAPP]
    int k = blockIdx.x * blockDim.x + threadIdx.x;
    if (k >= NPTS) return;
    float gmx = coords[2 * k]     * SCALE;
    float gmy = coords[2 * k + 1] * SCALE;
    int x0 = (((int)floorf(gmx - 3.0f)) + 1 + 512) & 255;
    int y0 = (((int)floorf(gmy - 3.0f)) + 1 + 512) & 255;
    int tx0 = x0 >> 3, tx1 = ((x0 + 5) & 255) >> 3;
    int ty0 = y0 >> 3, ty1 = ((y0 + 5) & 255) >> 3;
    int nx = (tx1 == tx0) ? 1 : 2;
    int ny = (ty1 == ty0) ? 1 : 2;
    int txs[2] = {tx0, tx1}, tys[2] = {ty0, ty1};
    for (int i = 0; i < nx; ++i)
        for (int j = 0; j < ny; ++j) {
            int tile = txs[i] * 32 + tys[j];
            unsigned pos = atomicAdd(&tileCount[tile], 1u);
            if (pos < CAPP) bins[tile * CAPP + pos] = (unsigned)k;
        }
}

// ---------- transpose values [img][k] -> vt [k][img] ----------
__global__ void k_transpose(const float* __restrict__ values, float* __restrict__ vt) {
    __shared__ float tile[32][257];
    int kbase = blockIdx.x * 256;
    int t = threadIdx.x;
    for (int img = 0; img < 32; ++img)
        tile[img][t] = values[img * NPTS + kbase + t];
    __syncthreads();
    int img = t & 31;
    int k0 = t >> 5;                   // 0..7
    for (int r = 0; r < 32; ++r) {
        int kl = k0 + r * 8;           // 0..255
        vt[(kbase + kl) * 32 + img] = tile[img][kl];
    }
}

// ---------- tile gather: per-cell LDS lists + register accumulation ----------
__global__ __launch_bounds__(256) void k_gather_tile(
        const float* __restrict__ coords, const float* __restrict__ wxy,
        const float* __restrict__ vt,
        const unsigned* __restrict__ tileCount, const unsigned* __restrict__ bins,
        float* __restrict__ grid) {
    __shared__ unsigned cnt[64];
    __shared__ unsigned lists[64 * CAPC];   // entry = (k:15 << 16) | (w:16)
    __shared__ unsigned kk[CAPP];
    __shared__ int xx[CAPP], yy[CAPP];
    int tile = blockIdx.x;                  // 0..1023
    int TX = tile >> 5, TY = tile & 31;
    int t = threadIdx.x;
    if (t < 64) cnt[t] = 0u;
    unsigned n = tileCount[tile];
    if (n > CAPP) n = CAPP;
    for (int p = t; p < (int)n; p += 256) {
        unsigned k = bins[tile * CAPP + p];
        kk[p] = k;
        float gmx = coords[2 * k]     * SCALE;
        float gmy = coords[2 * k + 1] * SCALE;
        xx[p] = ((int)floorf(gmx - 3.0f)) + 1 + 512;   // keep positive; &255 later
        yy[p] = ((int)floorf(gmy - 3.0f)) + 1 + 512;
    }
    __syncthreads();
    // stage A: build per-cell entry lists
    int total = (int)n * 36;
    for (int idx = t; idx < total; idx += 256) {
        int pi = idx / 36;
        int tap = idx - pi * 36;
        int jx = tap / 6, jy = tap - jx * 6;
        int cx = (xx[pi] + jx) & 255;
        int cy = (yy[pi] + jy) & 255;
        if ((cx >> 3) == TX && (cy >> 3) == TY) {
            unsigned k = kk[pi];
            float w = wxy[k * 12 + jx] * wxy[k * 12 + 6 + jy];
            unsigned q = (unsigned)(w * 65535.0f + 0.5f);
            if (q > 65535u) q = 65535u;
            int cl = ((cx & 7) << 3) | (cy & 7);
            unsigned pos = atomicAdd(&cnt[cl], 1u);    // native u32 LDS atomic
            if (pos < CAPC) lists[cl * CAPC + pos] = (k << 16) | q;
        }
    }
    __syncthreads();
    // stage B: thread owns (cell c, 8 images); pure register gather
    int c = t >> 2;
    int ib = (t & 3) * 8;
    unsigned nc = cnt[c];
    if (nc > CAPC) nc = CAPC;
    float acc0 = 0, acc1 = 0, acc2 = 0, acc3 = 0, acc4 = 0, acc5 = 0, acc6 = 0, acc7 = 0;
    for (unsigned e = 0; e < nc; ++e) {
        unsigned en = lists[c * CAPC + e];             // broadcast within quad
        float w = (float)(en & 0xFFFFu) * (1.0f / 65535.0f);
        const float* vp = &vt[(en >> 16) * 32 + ib];
        float4 va = *(const float4*)vp;
        float4 vb = *(const float4*)(vp + 4);
        acc0 += w * va.x; acc1 += w * va.y; acc2 += w * va.z; acc3 += w * va.w;
        acc4 += w * vb.x; acc5 += w * vb.y; acc6 += w * vb.z; acc7 += w * vb.w;
    }
    int gc = (((TX << 3) + (c >> 3)) << 8) | ((TY << 3) + (c & 7));
    float accs[8] = {acc0, acc1, acc2, acc3, acc4, acc5, acc6, acc7};
#pragma unroll
    for (int j = 0; j < 8; ++j)
        grid[(ib + j) * 65536 + gc] = accs[j];
}

// ---------- mm1: T1[img,p,v] = sum_u S[(u-2p)&255] * G[img,u,v] ----------
__global__ void k_mm1(const float* __restrict__ grid, const float2* __restrict__ S,
                      float2* __restrict__ T1) {
    __shared__ float2 ssh[256];
    int v = threadIdx.x;          // 0..255
    int img = blockIdx.x;         // 0..31
    int p0 = blockIdx.y * 4;      // 4 p-rows per block
    ssh[v] = S[v];
    __syncthreads();
    const float* g = grid + img * 65536;
    float re[4] = {0, 0, 0, 0}, im[4] = {0, 0, 0, 0};
    for (int u = 0; u < 256; ++u) {
        float gv = g[(u << 8) + v];
#pragma unroll
        for (int i = 0; i < 4; ++i) {
            float2 s = ssh[(u - 2 * (p0 + i)) & 255];
            re[i] += s.x * gv;
            im[i] += s.y * gv;
        }
    }
#pragma unroll
    for (int i = 0; i < 4; ++i)
        T1[((img * 128 + p0 + i) << 8) + v] = make_float2(re[i], im[i]);
}

// ---------- mm2: F[img,p,q] = sum_v T1[img,p,v] * S[(v-2q)&255]; |F| + fftshift ----------
__global__ void k_mm2(const float2* __restrict__ T1, const float2* __restrict__ S,
                      float* __restrict__ out) {
    __shared__ float sre[256], sim[256];
    __shared__ float2 trow[256];
    int q = threadIdx.x;          // 0..127
    int img = blockIdx.x;         // 0..31
    int p = blockIdx.y;           // 0..127
    float2 s0 = S[q];       sre[q] = s0.x;        sim[q] = s0.y;
    float2 s1 = S[q + 128]; sre[q + 128] = s1.x;  sim[q + 128] = s1.y;
    const float2* tr = T1 + (img * 128 + p) * 256;
    trow[q] = tr[q];
    trow[q + 128] = tr[q + 128];
    __syncthreads();
    float re = 0.f, im = 0.f;
    for (int v = 0; v < 256; ++v) {
        float2 t = trow[v];                  // wave-uniform -> LDS broadcast
        int si = (v - 2 * q) & 255;
        float srv = sre[si], siv = sim[si];
        re += t.x * srv - t.y * siv;
        im += t.x * siv + t.y * srv;
    }
    float mag = sqrtf(re * re + im * im);
    int b = img >> 2, c = img & 3;
    out[((((b ^ 4) * 4 + (c ^ 2)) * 128 + (p ^ 64)) << 7) + (q ^ 64)] = mag;
}

extern "C" void kernel_launch(void* const* d_in, const int* in_sizes, int n_in,
                              void* d_out, int out_size, void* d_ws, size_t ws_size,
                              hipStream_t stream) {
    const float* values = (const float*)d_in[0];   // [8,4,32768] f32
    const float* coords = (const float*)d_in[1];   // [32768,2] f32

    char* ws = (char*)d_ws;
    // layout (peak 19148800 B = 18.3 MB; 19.9 MB proven available in round 1):
    float2*   S         = (float2*)(ws + 0);             // 2 KB
    unsigned* tileCount = (unsigned*)(ws + 8192);        // 4 KB   [1024]
    float*    wxy       = (float*)(ws + 12288);          // 1.5 MB [32768*12]
    unsigned* bins      = (unsigned*)(ws + 1585152);     // 768 KB [1024*CAPP]
    float*    grid      = (float*)(ws + 2371584);        // 8 MB   [32][256][256]
    float2*   T1        = (float2*)(ws + 10760192);      // 8 MB   [32][128][256] c64
    float*    vt        = (float*)(ws + 10760192);       // 4 MB, overlaps T1 (dead before mm1)

    hipMemsetAsync(tileCount, 0, 1024 * sizeof(unsigned), stream);

    k_setup_S<<<1, 256, 0, stream>>>(S);
    k_weights<<<(NPTS * 2 + 255) / 256, 256, 0, stream>>>(coords, wxy);
    k_bin<<<(NPTS + 255) / 256, 256, 0, stream>>>(coords, tileCount, bins);
    k_transpose<<<NPTS / 256, 256, 0, stream>>>(values, vt);
    k_gather_tile<<<1024, 256, 0, stream>>>(coords, wxy, vt, tileCount, bins, grid);
    k_mm1<<<dim3(32, 32), 256, 0, stream>>>(grid, S, T1);
    k_mm2<<<dim3(32, 128), 128, 0, stream>>>(T1, S, (float*)d_out);
}

// Round 5
// 113.378 us; speedup vs baseline: 4.7481x; 1.4374x over previous
//
#include <hip/hip_runtime.h>
#include <math.h>

#define NPTS 32768
#define NIMG 32          // B*C = 8*4
#define CAPP 192         // per-tile point capacity (mean ~85, max ~126)
#define CAPC 57          // per-cell entry capacity (mean ~18, max ~46); odd -> bank-conflict-free
#define SCALE ((float)(256.0 / (2.0 * M_PI)))

// ---------- I0 Bessel (double, for setup) ----------
static __device__ __forceinline__ double bessel_i0d(double x) {
    double hx2 = 0.25 * x * x;
    double t = 1.0, s = 1.0;
#pragma unroll
    for (int m = 1; m <= 40; ++m) {
        t *= hx2 * (1.0 / ((double)m * (double)m));
        s += t;
    }
    return s;
}

// ---------- I0 Bessel (float) ----------
static __device__ __forceinline__ float bessel_i0f(float x) {
    float hx2 = 0.25f * x * x;
    float t = 1.0f, s = 1.0f;
#pragma unroll
    for (int m = 1; m <= 30; ++m) {
        t *= hx2 * (1.0f / ((float)m * (float)m));
        s += t;
    }
    return s;
}

// ---------- S[d] = sum_{x<128} ax[x] * exp(2*pi*i*x*d/256), table-based ----------
__global__ void k_setup_S(float2* __restrict__ S) {
    __shared__ double ere[256], eim[256];
    __shared__ float ax[128];
    int t = threadIdx.x;              // 0..255
    double ang = (double)t * (2.0 * M_PI / 256.0);
    ere[t] = cos(ang);                // one trig pair per thread (was 128)
    eim[t] = sin(ang);
    if (t < 128) {
        double i0a = bessel_i0d(14.04);
        double om = ((double)t - 63.5) * (1.0 / 256.0);
        double pj = M_PI * 6.0 * om;
        double tt = sqrt(14.04 * 14.04 - pj * pj);   // always real here
        double kbft = 6.0 * (sinh(tt) / tt) / i0a;
        ax[t] = (float)(1.0 / kbft);                 // apodization 1D
    }
    __syncthreads();
    double re = 0.0, im = 0.0;
    for (int x = 0; x < 128; ++x) {
        int ph = (x * t) & 255;                      // exact phase reduction
        re += (double)ax[x] * ere[ph];
        im += (double)ax[x] * eim[ph];
    }
    S[t] = make_float2((float)re, (float)im);
}

// ---------- fused per-point: 1D weights + 8x8 tile binning ----------
__global__ void k_prep(const float* __restrict__ coords, float* __restrict__ wxy,
                       unsigned* __restrict__ tileCount,   // [1024]
                       unsigned* __restrict__ bins) {      // [1024][CAPP]
    int k = blockIdx.x * blockDim.x + threadIdx.x;
    if (k >= NPTS) return;
    const float inv_i0a = 1.0f / bessel_i0f(14.04f);  // constant-folds
    float gmx = coords[2 * k]     * SCALE;
    float gmy = coords[2 * k + 1] * SCALE;
    float bxf = floorf(gmx - 3.0f), byf = floorf(gmy - 3.0f);
#pragma unroll
    for (int j = 0; j < 6; ++j) {
        float ux = gmx - (bxf + (float)(j + 1));
        float rx = ux * (1.0f / 3.0f);
        float argx = 1.0f - rx * rx;
        wxy[k * 12 + j] = (argx > 0.0f) ? bessel_i0f(14.04f * sqrtf(argx)) * inv_i0a : 0.0f;
        float uy = gmy - (byf + (float)(j + 1));
        float ry = uy * (1.0f / 3.0f);
        float argy = 1.0f - ry * ry;
        wxy[k * 12 + 6 + j] = (argy > 0.0f) ? bessel_i0f(14.04f * sqrtf(argy)) * inv_i0a : 0.0f;
    }
    int x0 = (((int)bxf) + 1 + 512) & 255;
    int y0 = (((int)byf) + 1 + 512) & 255;
    int tx0 = x0 >> 3, tx1 = ((x0 + 5) & 255) >> 3;
    int ty0 = y0 >> 3, ty1 = ((y0 + 5) & 255) >> 3;
    int nx = (tx1 == tx0) ? 1 : 2;
    int ny = (ty1 == ty0) ? 1 : 2;
    int txs[2] = {tx0, tx1}, tys[2] = {ty0, ty1};
    for (int i = 0; i < nx; ++i)
        for (int j = 0; j < ny; ++j) {
            int tile = txs[i] * 32 + tys[j];
            unsigned pos = atomicAdd(&tileCount[tile], 1u);
            if (pos < CAPP) bins[tile * CAPP + pos] = (unsigned)k;
        }
}

// ---------- transpose values [img][k] -> vt [k][img] ----------
__global__ void k_transpose(const float* __restrict__ values, float* __restrict__ vt) {
    __shared__ float tile[32][257];
    int kbase = blockIdx.x * 256;
    int t = threadIdx.x;
    for (int img = 0; img < 32; ++img)
        tile[img][t] = values[img * NPTS + kbase + t];
    __syncthreads();
    int img = t & 31;
    int k0 = t >> 5;                   // 0..7
    for (int r = 0; r < 32; ++r) {
        int kl = k0 + r * 8;           // 0..255
        vt[(kbase + kl) * 32 + img] = tile[img][kl];
    }
}

// ---------- tile gather: per-cell LDS lists + register accumulation ----------
__global__ __launch_bounds__(256) void k_gather_tile(
        const float* __restrict__ coords, const float* __restrict__ wxy,
        const float* __restrict__ vt,
        const unsigned* __restrict__ tileCount, const unsigned* __restrict__ bins,
        float* __restrict__ grid) {
    __shared__ unsigned cnt[64];
    __shared__ unsigned lists[64 * CAPC];   // entry = (k:15 << 16) | (w:16)
    __shared__ unsigned kk[CAPP];
    __shared__ int xx[CAPP], yy[CAPP];
    int tile = blockIdx.x;                  // 0..1023
    int TX = tile >> 5, TY = tile & 31;
    int t = threadIdx.x;
    if (t < 64) cnt[t] = 0u;
    unsigned n = tileCount[tile];
    if (n > CAPP) n = CAPP;
    for (int p = t; p < (int)n; p += 256) {
        unsigned k = bins[tile * CAPP + p];
        kk[p] = k;
        float gmx = coords[2 * k]     * SCALE;
        float gmy = coords[2 * k + 1] * SCALE;
        xx[p] = ((int)floorf(gmx - 3.0f)) + 1 + 512;   // keep positive; &255 later
        yy[p] = ((int)floorf(gmy - 3.0f)) + 1 + 512;
    }
    __syncthreads();
    // stage A: build per-cell entry lists
    int total = (int)n * 36;
    for (int idx = t; idx < total; idx += 256) {
        int pi = idx / 36;
        int tap = idx - pi * 36;
        int jx = tap / 6, jy = tap - jx * 6;
        int cx = (xx[pi] + jx) & 255;
        int cy = (yy[pi] + jy) & 255;
        if ((cx >> 3) == TX && (cy >> 3) == TY) {
            unsigned k = kk[pi];
            float w = wxy[k * 12 + jx] * wxy[k * 12 + 6 + jy];
            unsigned q = (unsigned)(w * 65535.0f + 0.5f);
            if (q > 65535u) q = 65535u;
            int cl = ((cx & 7) << 3) | (cy & 7);
            unsigned pos = atomicAdd(&cnt[cl], 1u);    // native u32 LDS atomic
            if (pos < CAPC) lists[cl * CAPC + pos] = (k << 16) | q;
        }
    }
    __syncthreads();
    // stage B: thread owns (cell c, 8 images); pure register gather
    int c = t >> 2;
    int ib = (t & 3) * 8;
    unsigned nc = cnt[c];
    if (nc > CAPC) nc = CAPC;
    float acc0 = 0, acc1 = 0, acc2 = 0, acc3 = 0, acc4 = 0, acc5 = 0, acc6 = 0, acc7 = 0;
    for (unsigned e = 0; e < nc; ++e) {
        unsigned en = lists[c * CAPC + e];             // broadcast within quad
        float w = (float)(en & 0xFFFFu) * (1.0f / 65535.0f);
        const float* vp = &vt[(en >> 16) * 32 + ib];
        float4 va = *(const float4*)vp;
        float4 vb = *(const float4*)(vp + 4);
        acc0 += w * va.x; acc1 += w * va.y; acc2 += w * va.z; acc3 += w * va.w;
        acc4 += w * vb.x; acc5 += w * vb.y; acc6 += w * vb.z; acc7 += w * vb.w;
    }
    int gc = (((TX << 3) + (c >> 3)) << 8) | ((TY << 3) + (c & 7));
    float accs[8] = {acc0, acc1, acc2, acc3, acc4, acc5, acc6, acc7};
#pragma unroll
    for (int j = 0; j < 8; ++j)
        grid[(ib + j) * 65536 + gc] = accs[j];
}

// ---------- fused mm: per (img, 4-row p-band): T1 rows in LDS, then F rows + |.| ----------
__global__ __launch_bounds__(256) void k_mm(const float* __restrict__ grid,
                                            const float2* __restrict__ S,
                                            float* __restrict__ out) {
    __shared__ float2 ssh[256];            // S, for stage 1 (broadcast reads)
    __shared__ float2 Se[128], So[128];    // even/odd split, for stage 2 (stride-1 reads)
    __shared__ float2 trow[4][256];        // the 4 T1 rows of this p-band
    int t = threadIdx.x;
    int p0 = blockIdx.x * 4;               // p-band
    int img = blockIdx.y;
    float2 sv = S[t];
    ssh[t] = sv;
    if (t < 128) {
        Se[t] = S[2 * t];
        So[t] = S[2 * t + 1];
    }
    __syncthreads();
    // stage 1: T1[p0+i][t] = sum_u S[(u-2(p0+i))&255] * G[img][u][t]
    const float* g = grid + img * 65536;
    float re[4] = {0, 0, 0, 0}, im[4] = {0, 0, 0, 0};
    for (int u = 0; u < 256; ++u) {
        float gv = g[(u << 8) + t];
#pragma unroll
        for (int i = 0; i < 4; ++i) {
            float2 s = ssh[(u - 2 * (p0 + i)) & 255];   // wave-uniform -> broadcast
            re[i] += s.x * gv;
            im[i] += s.y * gv;
        }
    }
#pragma unroll
    for (int i = 0; i < 4; ++i)
        trow[i][t] = make_float2(re[i], im[i]);
    __syncthreads();
    // stage 2: F[p][q] = sum_v T1[p][v]*S[(v-2q)&255]; v=2h+par -> stride-1 LDS
    int b = img >> 2, c = img & 3;
    int obase = ((b ^ 4) * 4 + (c ^ 2)) * 128;
#pragma unroll
    for (int half = 0; half < 2; ++half) {
        int i = half * 2 + (t >> 7);       // row within band
        int q = t & 127;
        const float2* tr = trow[i];
        float rr = 0.f, ii = 0.f;
        for (int h = 0; h < 128; ++h) {
            int m = (h - q) & 127;
            float2 t0 = tr[2 * h];         // broadcast
            float2 t1 = tr[2 * h + 1];     // broadcast
            float2 se = Se[m];             // stride-1 across lanes
            float2 so = So[m];
            rr += t0.x * se.x - t0.y * se.y;
            ii += t0.x * se.y + t0.y * se.x;
            rr += t1.x * so.x - t1.y * so.y;
            ii += t1.x * so.y + t1.y * so.x;
        }
        int p = p0 + i;
        out[((obase + (p ^ 64)) << 7) + (q ^ 64)] = sqrtf(rr * rr + ii * ii);
    }
}

extern "C" void kernel_launch(void* const* d_in, const int* in_sizes, int n_in,
                              void* d_out, int out_size, void* d_ws, size_t ws_size,
                              hipStream_t stream) {
    const float* values = (const float*)d_in[0];   // [8,4,32768] f32
    const float* coords = (const float*)d_in[1];   // [32768,2] f32

    char* ws = (char*)d_ws;
    // layout (peak ~14.7 MB):
    float2*   S         = (float2*)(ws + 0);             // 2 KB
    unsigned* tileCount = (unsigned*)(ws + 8192);        // 4 KB   [1024]
    float*    wxy       = (float*)(ws + 12288);          // 1.5 MB [32768*12]
    unsigned* bins      = (unsigned*)(ws + 1585152);     // 768 KB [1024*CAPP]
    float*    grid      = (float*)(ws + 2371584);        // 8 MB   [32][256][256]
    float*    vt        = (float*)(ws + 10760192);       // 4 MB   [32768][32]

    hipMemsetAsync(tileCount, 0, 1024 * sizeof(unsigned), stream);

    k_setup_S<<<1, 256, 0, stream>>>(S);
    k_prep<<<(NPTS + 255) / 256, 256, 0, stream>>>(coords, wxy, tileCount, bins);
    k_transpose<<<NPTS / 256, 256, 0, stream>>>(values, vt);
    k_gather_tile<<<1024, 256, 0, stream>>>(coords, wxy, vt, tileCount, bins, grid);
    k_mm<<<dim3(32, 32), 256, 0, stream>>>(grid, S, (float*)d_out);
}